// Round 7
// baseline (207.008 us; speedup 1.0000x reference)
//
#include <hip/hip_runtime.h>
#include <stdint.h>

static constexpr int BB = 32;
static constexpr int TT = 2048;
static constexpr int DD = 512;
static constexpr int LMAX = 320;   // >= kmax = ceil(2048*0.15) = 308

// ---------------------------------------------------------------------------
// Kernel 1: per-(b,t) L2 norm -> 32-bit order key. 8 rows per wave (16
// outstanding float4 loads per thread for deep MLP); lane 0 stores the 8
// consecutive keys as two uint4s. key = bits(sqrt(sumsq))+1 if t<len else 0;
// nonneg float bits are monotone, +1 keeps every valid key > every masked key.
// Per-row summation order identical to prior rounds -> bitwise-same keys.
// ---------------------------------------------------------------------------
__global__ __launch_bounds__(256) void topq_norms(
    const float* __restrict__ H, const int* __restrict__ lengths,
    unsigned int* __restrict__ keys)
{
    const int wave = threadIdx.x >> 6;
    const int lane = threadIdx.x & 63;
    const int base = (blockIdx.x * 4 + wave) * 8;        // first of 8 rows; 8 | base
    const int b    = base >> 11;                          // rows never cross b (8 | 2048)
    const int len  = lengths[b];
    const float4* p = reinterpret_cast<const float4*>(H) + (size_t)base * (DD / 4);

    float s[8];
    #pragma unroll
    for (int r = 0; r < 8; ++r) {
        float4 a = p[r * (DD / 4) + lane];
        float4 c = p[r * (DD / 4) + lane + 64];
        s[r] = a.x*a.x + a.y*a.y + a.z*a.z + a.w*a.w
             + c.x*c.x + c.y*c.y + c.z*c.z + c.w*c.w;
    }
    #pragma unroll
    for (int off = 32; off; off >>= 1) {
        #pragma unroll
        for (int r = 0; r < 8; ++r) s[r] += __shfl_xor(s[r], off);
    }
    if (lane == 0) {
        const int t0 = base & (TT - 1);
        uint4 kv0, kv1;
        kv0.x = (t0 + 0 < len) ? __float_as_uint(sqrtf(s[0])) + 1u : 0u;
        kv0.y = (t0 + 1 < len) ? __float_as_uint(sqrtf(s[1])) + 1u : 0u;
        kv0.z = (t0 + 2 < len) ? __float_as_uint(sqrtf(s[2])) + 1u : 0u;
        kv0.w = (t0 + 3 < len) ? __float_as_uint(sqrtf(s[3])) + 1u : 0u;
        kv1.x = (t0 + 4 < len) ? __float_as_uint(sqrtf(s[4])) + 1u : 0u;
        kv1.y = (t0 + 5 < len) ? __float_as_uint(sqrtf(s[5])) + 1u : 0u;
        kv1.z = (t0 + 6 < len) ? __float_as_uint(sqrtf(s[6])) + 1u : 0u;
        kv1.w = (t0 + 7 < len) ? __float_as_uint(sqrtf(s[7])) + 1u : 0u;
        *reinterpret_cast<uint4*>(keys + base)     = kv0;
        *reinterpret_cast<uint4*>(keys + base + 4) = kv1;
    }
}

// ---------------------------------------------------------------------------
// Kernel 2: fused select + pool, grid (B, 8) x 256 threads. Each block selects
// (redundantly across the 8 column-eighth blocks -- parallel CUs, free wall
// time) and pools its 64-column slice.
//
// Select (wave 0, register-resident, barrier-free): binary search for the max
// threshold v with count(key >= v) >= k over [min_valid_key, max_key+1).
// Then count(>v)=cgt < k and m = k-cgt of the ==v elements are taken in
// ascending-t order (fast path m==ceq needs no ordering; ballot slow path
// only on exact fp32 norm ties). Reproduces jax.lax.top_k's selected set.
//
// Pool: 16 row-groups x 16 float4-column-groups; 4-deep unrolled float4
// gathers (L3-resident H), LDS tree-reduce, /k exact.
// ---------------------------------------------------------------------------
__global__ __launch_bounds__(256) void topq_selpool(
    const unsigned int* __restrict__ keys, const int* __restrict__ lengths,
    const float* __restrict__ H, float* __restrict__ out)
{
    __shared__ unsigned int   sk[TT];        // 8 KB
    __shared__ unsigned short slist[LMAX];
    __shared__ float4 sred[16][16];          // 4 KB
    __shared__ int scount;
    __shared__ int skk;

    const int b   = blockIdx.x;
    const int q   = blockIdx.y;              // column eighth 0..7
    const int tid = threadIdx.x;

    // stage keys: two uint4s per thread
    {
        const uint4* src = reinterpret_cast<const uint4*>(keys + b * TT);
        uint4* dst = reinterpret_cast<uint4*>(sk);
        dst[tid]       = src[tid];
        dst[tid + 256] = src[tid + 256];
    }
    if (tid == 0) scount = 0;
    __syncthreads();

    if (tid < 64) {                          // wave 0 does the whole selection
        const int lane = tid;
        unsigned int kreg[32];
        #pragma unroll
        for (int j = 0; j < 32; ++j) kreg[j] = sk[j * 64 + lane];

        const int len = lengths[b];
        int k = (int)ceilf((float)len * 0.15f);   // fp32 math to bit-match JAX
        if (k < 1) k = 1;

        // wave-wide [min valid key, max key]
        unsigned int mn = 0xFFFFFFFFu, mx = 0u;
        #pragma unroll
        for (int j = 0; j < 32; ++j) {
            const unsigned int kk = kreg[j];
            if (kk != 0u && kk < mn) mn = kk;
            if (kk > mx) mx = kk;
        }
        #pragma unroll
        for (int off = 32; off; off >>= 1) {
            const unsigned int mno = (unsigned int)__shfl_xor((int)mn, off);
            const unsigned int mxo = (unsigned int)__shfl_xor((int)mx, off);
            mn = mn < mno ? mn : mno;
            mx = mx > mxo ? mx : mxo;
        }

        // max v with count(key >= v) >= k;  lo=mn: count=len>=k, hi=mx+1: count=0
        unsigned int lo = mn, hi = mx + 1u;
        while (hi - lo > 1u) {
            const unsigned int mid = lo + ((hi - lo) >> 1);
            int cnt = 0;
            #pragma unroll
            for (int j = 0; j < 32; ++j) cnt += (kreg[j] >= mid) ? 1 : 0;
            #pragma unroll
            for (int off = 32; off; off >>= 1) cnt += __shfl_xor(cnt, off);
            if (cnt >= k) lo = mid; else hi = mid;   // wave-uniform
        }
        const unsigned int v = lo;

        int cgt = 0, ceq = 0;
        #pragma unroll
        for (int j = 0; j < 32; ++j) {
            cgt += (kreg[j] > v)  ? 1 : 0;
            ceq += (kreg[j] == v) ? 1 : 0;
        }
        #pragma unroll
        for (int off = 32; off; off >>= 1) {
            cgt += __shfl_xor(cgt, off);
            ceq += __shfl_xor(ceq, off);
        }
        const int m = k - cgt;               // in [1, ceq]

        #pragma unroll
        for (int j = 0; j < 32; ++j) {
            if (kreg[j] > v) {
                const int p = atomicAdd(&scount, 1);
                slist[p] = (unsigned short)(j * 64 + lane);
            }
        }
        if (m == ceq) {                      // common case: take all ==v
            #pragma unroll
            for (int j = 0; j < 32; ++j) {
                if (kreg[j] == v) {
                    const int p = atomicAdd(&scount, 1);
                    slist[p] = (unsigned short)(j * 64 + lane);
                }
            }
        } else {                             // exact ties: first m in t-order
            const unsigned long long ltmask = (1ull << lane) - 1ull;
            int taken = 0;
            for (int c = 0; c < TT / 64 && taken < m; ++c) {
                const int t = c * 64 + lane;
                const bool pred = (sk[t] == v);
                const unsigned long long mask = __ballot(pred);
                const int rank = taken + __popcll(mask & ltmask);
                if (pred && rank < m) {
                    const int p = atomicAdd(&scount, 1);
                    slist[p] = (unsigned short)t;
                }
                taken += __popcll(mask);
            }
        }
        if (lane == 0) skk = k;
    }
    __syncthreads();

    const int k  = skk;
    const int r  = tid >> 4;                 // row group 0..15
    const int cg = tid & 15;                 // float4 column group 0..15
    const float4* Hb4 =
        reinterpret_cast<const float4*>(H + (size_t)b * TT * DD);
    const int col4 = q * 16 + cg;

    float4 a0 = {0.f, 0.f, 0.f, 0.f}, a1 = {0.f, 0.f, 0.f, 0.f};
    float4 a2 = {0.f, 0.f, 0.f, 0.f}, a3 = {0.f, 0.f, 0.f, 0.f};
    int j = r;
    for (; j + 48 < k; j += 64) {            // 4 independent gathers in flight
        const int t0 = slist[j],      t1 = slist[j + 16];
        const int t2 = slist[j + 32], t3 = slist[j + 48];
        const float4 x0 = Hb4[(size_t)t0 * 128 + col4];
        const float4 x1 = Hb4[(size_t)t1 * 128 + col4];
        const float4 x2 = Hb4[(size_t)t2 * 128 + col4];
        const float4 x3 = Hb4[(size_t)t3 * 128 + col4];
        a0.x += x0.x; a0.y += x0.y; a0.z += x0.z; a0.w += x0.w;
        a1.x += x1.x; a1.y += x1.y; a1.z += x1.z; a1.w += x1.w;
        a2.x += x2.x; a2.y += x2.y; a2.z += x2.z; a2.w += x2.w;
        a3.x += x3.x; a3.y += x3.y; a3.z += x3.z; a3.w += x3.w;
    }
    for (; j < k; j += 16) {
        const float4 x0 = Hb4[(size_t)slist[j] * 128 + col4];
        a0.x += x0.x; a0.y += x0.y; a0.z += x0.z; a0.w += x0.w;
    }
    a0.x += a1.x + a2.x + a3.x;
    a0.y += a1.y + a2.y + a3.y;
    a0.z += a1.z + a2.z + a3.z;
    a0.w += a1.w + a2.w + a3.w;
    sred[r][cg] = a0;
    __syncthreads();

    if (tid < 16) {
        float4 s = {0.f, 0.f, 0.f, 0.f};
        #pragma unroll
        for (int rr = 0; rr < 16; ++rr) {
            const float4 x = sred[rr][tid];
            s.x += x.x; s.y += x.y; s.z += x.z; s.w += x.w;
        }
        const float kf = (float)k;
        float4 o;
        o.x = s.x / kf; o.y = s.y / kf; o.z = s.z / kf; o.w = s.w / kf;
        reinterpret_cast<float4*>(out)[b * 128 + q * 16 + tid] = o;
    }
}

// ---------------------------------------------------------------------------
extern "C" void kernel_launch(void* const* d_in, const int* in_sizes, int n_in,
                              void* d_out, int out_size, void* d_ws, size_t ws_size,
                              hipStream_t stream)
{
    const float* H       = (const float*)d_in[0];
    const int*   lengths = (const int*)d_in[1];
    float*       out     = (float*)d_out;

    unsigned int* keys = (unsigned int*)d_ws;    // 256 KB of ws

    topq_norms  <<<dim3(BB * TT / 32), 256, 0, stream>>>(H, lengths, keys);
    topq_selpool<<<dim3(BB, 8),        256, 0, stream>>>(keys, lengths, H, out);
}

// Round 8
// 204.284 us; speedup vs baseline: 1.0133x; 1.0133x over previous
//
#include <hip/hip_runtime.h>
#include <stdint.h>

static constexpr int BB = 32;
static constexpr int TT = 2048;
static constexpr int DD = 512;
static constexpr int LMAX = 320;   // >= kmax = ceil(2048*0.15) = 308

// ---------------------------------------------------------------------------
// Kernel 1: per-(b,t) L2 norm -> 32-bit order key. 4 rows per wave (4
// independent shfl-reduce chains interleave for ILP); lane 0 stores the 4
// consecutive keys as one uint4. key = bits(sqrt(sumsq))+1 if t<len else 0;
// nonneg float bits are monotone, +1 keeps every valid key > every masked key.
// ---------------------------------------------------------------------------
__global__ __launch_bounds__(256) void topq_norms(
    const float* __restrict__ H, const int* __restrict__ lengths,
    unsigned int* __restrict__ keys)
{
    const int wave = threadIdx.x >> 6;
    const int lane = threadIdx.x & 63;
    const int base = (blockIdx.x * 4 + wave) * 4;        // first of 4 rows; 4 | base
    const int b    = base >> 11;                          // rows never cross b (4 | 2048)
    const int len  = lengths[b];
    const float4* p = reinterpret_cast<const float4*>(H) + (size_t)base * (DD / 4);

    float s[4];
    #pragma unroll
    for (int r = 0; r < 4; ++r) {
        float4 a = p[r * (DD / 4) + lane];
        float4 c = p[r * (DD / 4) + lane + 64];
        s[r] = a.x*a.x + a.y*a.y + a.z*a.z + a.w*a.w
             + c.x*c.x + c.y*c.y + c.z*c.z + c.w*c.w;
    }
    #pragma unroll
    for (int off = 32; off; off >>= 1) {
        #pragma unroll
        for (int r = 0; r < 4; ++r) s[r] += __shfl_xor(s[r], off);
    }
    if (lane == 0) {
        const int t0 = base & (TT - 1);
        uint4 kv;
        kv.x = (t0 + 0 < len) ? __float_as_uint(sqrtf(s[0])) + 1u : 0u;
        kv.y = (t0 + 1 < len) ? __float_as_uint(sqrtf(s[1])) + 1u : 0u;
        kv.z = (t0 + 2 < len) ? __float_as_uint(sqrtf(s[2])) + 1u : 0u;
        kv.w = (t0 + 3 < len) ? __float_as_uint(sqrtf(s[3])) + 1u : 0u;
        *reinterpret_cast<uint4*>(keys + base) = kv;
    }
}

// ---------------------------------------------------------------------------
// Kernel 2: fused select + pool, grid (B, 4). Each block selects (redundantly
// across the 4 column-quarter blocks -- parallel CUs, free wall time) and
// pools its 128-column slice.
//
// Select (wave 0, register-resident, barrier-free): binary search for the max
// threshold v with count(key >= v) >= k over [min_valid_key, max_key+1)
// (~22 iterations for concentrated norm keys). Then count(>v)=cgt < k and
// m = k-cgt of the ==v elements are taken in ascending-t order (fast path
// m==ceq needs no ordering; ballot slow path only on exact fp32 norm ties).
// Exactly reproduces jax.lax.top_k's set (ties -> lower index).
//
// Pool: 16 row-groups x 32 float4-column-groups; float4 gathers (each
// half-wave reads a contiguous 512B row segment), LDS tree-reduce, /k exact.
// ---------------------------------------------------------------------------
__global__ __launch_bounds__(512) void topq_selpool(
    const unsigned int* __restrict__ keys, const int* __restrict__ lengths,
    const float* __restrict__ H, float* __restrict__ out)
{
    __shared__ unsigned int   sk[TT];        // 8 KB
    __shared__ unsigned short slist[LMAX];
    __shared__ float4 sred[16][32];          // 8 KB
    __shared__ int scount;
    __shared__ int skk;

    const int b   = blockIdx.x;
    const int q   = blockIdx.y;
    const int tid = threadIdx.x;

    // stage keys: one uint4 per thread
    reinterpret_cast<uint4*>(sk)[tid] =
        reinterpret_cast<const uint4*>(keys + b * TT)[tid];
    if (tid == 0) scount = 0;
    __syncthreads();

    if (tid < 64) {                          // wave 0 does the whole selection
        const int lane = tid;
        unsigned int kreg[32];
        #pragma unroll
        for (int j = 0; j < 32; ++j) kreg[j] = sk[j * 64 + lane];

        const int len = lengths[b];
        int k = (int)ceilf((float)len * 0.15f);   // fp32 math to bit-match JAX
        if (k < 1) k = 1;

        // wave-wide [min valid key, max key]
        unsigned int mn = 0xFFFFFFFFu, mx = 0u;
        #pragma unroll
        for (int j = 0; j < 32; ++j) {
            const unsigned int kk = kreg[j];
            if (kk != 0u && kk < mn) mn = kk;
            if (kk > mx) mx = kk;
        }
        #pragma unroll
        for (int off = 32; off; off >>= 1) {
            const unsigned int mno = (unsigned int)__shfl_xor((int)mn, off);
            const unsigned int mxo = (unsigned int)__shfl_xor((int)mx, off);
            mn = mn < mno ? mn : mno;
            mx = mx > mxo ? mx : mxo;
        }

        // max v with count(key >= v) >= k;  lo=mn: count=len>=k, hi=mx+1: count=0
        unsigned int lo = mn, hi = mx + 1u;
        while (hi - lo > 1u) {
            const unsigned int mid = lo + ((hi - lo) >> 1);
            int cnt = 0;
            #pragma unroll
            for (int j = 0; j < 32; ++j) cnt += (kreg[j] >= mid) ? 1 : 0;
            #pragma unroll
            for (int off = 32; off; off >>= 1) cnt += __shfl_xor(cnt, off);
            if (cnt >= k) lo = mid; else hi = mid;   // wave-uniform
        }
        const unsigned int v = lo;

        int cgt = 0, ceq = 0;
        #pragma unroll
        for (int j = 0; j < 32; ++j) {
            cgt += (kreg[j] > v)  ? 1 : 0;
            ceq += (kreg[j] == v) ? 1 : 0;
        }
        #pragma unroll
        for (int off = 32; off; off >>= 1) {
            cgt += __shfl_xor(cgt, off);
            ceq += __shfl_xor(ceq, off);
        }
        const int m = k - cgt;               // in [1, ceq]

        #pragma unroll
        for (int j = 0; j < 32; ++j) {
            if (kreg[j] > v) {
                const int p = atomicAdd(&scount, 1);
                slist[p] = (unsigned short)(j * 64 + lane);
            }
        }
        if (m == ceq) {                      // common case: take all ==v
            #pragma unroll
            for (int j = 0; j < 32; ++j) {
                if (kreg[j] == v) {
                    const int p = atomicAdd(&scount, 1);
                    slist[p] = (unsigned short)(j * 64 + lane);
                }
            }
        } else {                             // exact ties: first m in t-order
            const unsigned long long ltmask = (1ull << lane) - 1ull;
            int taken = 0;
            for (int c = 0; c < TT / 64 && taken < m; ++c) {
                const int t = c * 64 + lane;
                const bool pred = (sk[t] == v);
                const unsigned long long mask = __ballot(pred);
                const int rank = taken + __popcll(mask & ltmask);
                if (pred && rank < m) {
                    const int p = atomicAdd(&scount, 1);
                    slist[p] = (unsigned short)t;
                }
                taken += __popcll(mask);
            }
        }
        if (lane == 0) skk = k;
    }
    __syncthreads();

    const int k  = skk;
    const int r  = tid >> 5;                 // row group 0..15
    const int cg = tid & 31;                 // float4 column group
    const float4* Hb4 =
        reinterpret_cast<const float4*>(H + (size_t)b * TT * DD);
    const int col4 = q * 32 + cg;

    float4 a0 = {0.f, 0.f, 0.f, 0.f}, a1 = {0.f, 0.f, 0.f, 0.f};
    int j = r;
    for (; j + 16 < k; j += 32) {
        const int t0 = slist[j], t1 = slist[j + 16];
        const float4 x0 = Hb4[(size_t)t0 * 128 + col4];
        const float4 x1 = Hb4[(size_t)t1 * 128 + col4];
        a0.x += x0.x; a0.y += x0.y; a0.z += x0.z; a0.w += x0.w;
        a1.x += x1.x; a1.y += x1.y; a1.z += x1.z; a1.w += x1.w;
    }
    if (j < k) {
        const float4 x0 = Hb4[(size_t)slist[j] * 128 + col4];
        a0.x += x0.x; a0.y += x0.y; a0.z += x0.z; a0.w += x0.w;
    }
    a0.x += a1.x; a0.y += a1.y; a0.z += a1.z; a0.w += a1.w;
    sred[r][cg] = a0;
    __syncthreads();

    if (tid < 32) {
        float4 s = {0.f, 0.f, 0.f, 0.f};
        #pragma unroll
        for (int rr = 0; rr < 16; ++rr) {
            const float4 x = sred[rr][tid];
            s.x += x.x; s.y += x.y; s.z += x.z; s.w += x.w;
        }
        const float kf = (float)k;
        float4 o;
        o.x = s.x / kf; o.y = s.y / kf; o.z = s.z / kf; o.w = s.w / kf;
        reinterpret_cast<float4*>(out)[b * 128 + q * 32 + tid] = o;
    }
}

// ---------------------------------------------------------------------------
extern "C" void kernel_launch(void* const* d_in, const int* in_sizes, int n_in,
                              void* d_out, int out_size, void* d_ws, size_t ws_size,
                              hipStream_t stream)
{
    const float* H       = (const float*)d_in[0];
    const int*   lengths = (const int*)d_in[1];
    float*       out     = (float*)d_out;

    unsigned int* keys = (unsigned int*)d_ws;    // 256 KB of ws

    topq_norms  <<<dim3(BB * TT / 16), 256, 0, stream>>>(H, lengths, keys);
    topq_selpool<<<dim3(BB, 4),        512, 0, stream>>>(keys, lengths, H, out);
}